// Round 9
// baseline (416.432 us; speedup 1.0000x reference)
//
#include <hip/hip_runtime.h>
#include <hip/hip_bf16.h>

typedef short bf16x8 __attribute__((ext_vector_type(8)));
typedef float f32x4  __attribute__((ext_vector_type(4)));

#define T_SEQ 4096
#define NB    4
#define E_DIM 2048
#define D_DIM 128
#define M_TOT (NB * T_SEQ)  // 16384
#define NCHUNK 4
#define CHUNK_KT 16
#define SM_SHIFT 12.0f

__device__ __forceinline__ ushort f2bf(float f) {
  union { float f; unsigned u; } c; c.f = f;
  unsigned u = c.u;
  unsigned r = (u + 0x7FFFu + ((u >> 16) & 1u)) >> 16;  // RNE
  return (ushort)r;
}
__device__ __forceinline__ float bf2f(ushort u) {
  union { unsigned u; float f; } c; c.u = ((unsigned)u) << 16;
  return c.f;
}
// 8 fp32 -> bf16x8 via packed RNE converts
__device__ __forceinline__ bf16x8 cvt8(const float4& lo, const float4& hi) {
  union { __hip_bfloat162 h; ushort u[2]; } t;
  union { ushort u[8]; bf16x8 v; } r;
  t.h = __float22bfloat162_rn(make_float2(lo.x, lo.y)); r.u[0] = t.u[0]; r.u[1] = t.u[1];
  t.h = __float22bfloat162_rn(make_float2(lo.z, lo.w)); r.u[2] = t.u[0]; r.u[3] = t.u[1];
  t.h = __float22bfloat162_rn(make_float2(hi.x, hi.y)); r.u[4] = t.u[0]; r.u[5] = t.u[1];
  t.h = __float22bfloat162_rn(make_float2(hi.z, hi.w)); r.u[6] = t.u[0]; r.u[7] = t.u[1];
  return r.v;
}

// async global -> LDS, 16 bytes per lane; lds dest must be wave-uniform base
__device__ __forceinline__ void gl2lds16(const void* g, void* l) {
  __builtin_amdgcn_global_load_lds(
      (const __attribute__((address_space(1))) unsigned int*)g,
      (__attribute__((address_space(3))) unsigned int*)l, 16, 0, 0);
}

// ---------------- kernel 1: Wt[o*128+n][k] = W_o[k][n]  (bf16, tiled) ----------------
// grid (E/64=32, 128/64=2, 3)
__global__ __launch_bounds__(256) void build_wt(const float* __restrict__ Wq,
                                                const float* __restrict__ Wk,
                                                const float* __restrict__ Wv,
                                                ushort* __restrict__ Wt) {
  __shared__ ushort tile[64][72];   // [k-local][n-local]
  const int tid = threadIdx.x;
  const int k0 = blockIdx.x * 64, n0 = blockIdx.y * 64, o = blockIdx.z;
  const float* W = (o == 0) ? Wq : ((o == 1) ? Wk : Wv);
  for (int i = 0; i < 4; i++) {
    int c = tid + i * 256;
    int r = c >> 4, c4 = (c & 15) * 4;
    float4 v = *(const float4*)(W + (size_t)(k0 + r) * D_DIM + n0 + c4);
    ushort4 b4;
    b4.x = f2bf(v.x); b4.y = f2bf(v.y); b4.z = f2bf(v.z); b4.w = f2bf(v.w);
    *(ushort4*)(&tile[r][c4]) = b4;
  }
  __syncthreads();
  for (int i = 0; i < 2; i++) {
    int c = tid + i * 256;
    int nn = c >> 3, k8 = (c & 7) * 8;
    ushort tmp[8];
    for (int j = 0; j < 8; j++) tmp[j] = tile[k8 + j][nn];
    *(uint4*)(Wt + (size_t)((o << 7) + n0 + nn) * E_DIM + k0 + k8) = *(const uint4*)tmp;
  }
}

// ---------------- kernel 2: QKV GEMM + fused V-transpose epilogue ----------------
// ROUND-5 core (best measured: 92.4 us, occ 38%, VGPR 52). BM=64, BN=96, BK=64;
// grid (256,4) = 1024 blocks = 4/CU (LDS 40KB).
__global__ __launch_bounds__(256, 4) void qkv_gemm(const float* __restrict__ x,
                                                   const ushort* __restrict__ Wt,
                                                   ushort* __restrict__ Q,
                                                   ushort* __restrict__ K,
                                                   ushort* __restrict__ Vt) {
  __shared__ ushort As[2][64 * 64];   // [m][k] bf16, swizzled 16B groups (16 KB)
  __shared__ ushort Bs[2][96 * 64];   // [n][k] bf16, swizzled 16B groups (24 KB)

  const int tid  = threadIdx.x;
  const int wave = tid >> 6, lane = tid & 63;
  const int quad = lane >> 4, l16 = lane & 15;
  const int wm = wave >> 1, wn = wave & 1;   // 2x2 waves, wave tile 32x48
  const int m0 = blockIdx.x * 64;
  const int n0 = blockIdx.y * 96;

  f32x4 acc[2][3] = {};

  // B DMA slot geometry: slot s (16B) holds row n = s>>3; physical group p = s&7
  // stores logical col-group cg = p ^ (n&7)
  const int s_ = wave * 64 + lane;
  const int n_ = s_ >> 3, p_ = s_ & 7;

  // A staging geometry: thread t owns row r = t>>2, k-quarter q4 = t&3 (16 floats)
  const int ar_ = tid >> 2, aq4_ = tid & 3;
  const float* xrow = x + (size_t)(m0 + ar_) * E_DIM + aq4_ * 16;

#define DMA_B(k0_, buf_)                                                        \
  _Pragma("unroll")                                                             \
  for (int i_ = 0; i_ < 3; i_++) {                                              \
    int slotbase = i_ * 256 + wave * 64;                                        \
    int n = (i_ * 32) + n_;            /* = (slotbase+lane)>>3 */               \
    int cg = p_ ^ (n & 7);                                                      \
    gl2lds16(Wt + (size_t)(n0 + n) * E_DIM + (k0_) + cg * 8,                    \
             (char*)(buf_) + (size_t)slotbase * 16);                            \
  }

#define GLOAD_A(k0_)                                                            \
  {                                                                             \
    const float* ap_ = xrow + (k0_);                                            \
    areg0 = *(const float4*)(ap_);                                              \
    areg1 = *(const float4*)(ap_ + 4);                                          \
    areg2 = *(const float4*)(ap_ + 8);                                          \
    areg3 = *(const float4*)(ap_ + 12);                                         \
  }

#define CVT_WRITE_A(bufidx)                                                     \
  {                                                                             \
    ushort* as_ = As[bufidx];                                                   \
    bf16x8 w0_ = cvt8(areg0, areg1);                                            \
    bf16x8 w1_ = cvt8(areg2, areg3);                                            \
    *(bf16x8*)(as_ + ar_ * 64 + (((aq4_ * 2)     ^ (ar_ & 7)) * 8)) = w0_;      \
    *(bf16x8*)(as_ + ar_ * 64 + (((aq4_ * 2 + 1) ^ (ar_ & 7)) * 8)) = w1_;      \
  }

#define COMPUTE(bufidx)                                                         \
  {                                                                             \
    const ushort* as_ = As[bufidx];                                             \
    const ushort* bs_ = Bs[bufidx];                                             \
    _Pragma("unroll")                                                           \
    for (int kk = 0; kk < 2; kk++) {                                            \
      const int slot = ((kk * 4 + quad) ^ (l16 & 7)) * 8;                       \
      bf16x8 af0 = *(const bf16x8*)(as_ + (wm * 32 + l16) * 64 + slot);         \
      bf16x8 af1 = *(const bf16x8*)(as_ + (wm * 32 + 16 + l16) * 64 + slot);    \
      _Pragma("unroll")                                                         \
      for (int ni = 0; ni < 3; ni++) {                                          \
        int n = wn * 48 + ni * 16 + l16;                                        \
        bf16x8 bf = *(const bf16x8*)(bs_ + n * 64 + slot);                      \
        acc[0][ni] = __builtin_amdgcn_mfma_f32_16x16x32_bf16(af0, bf, acc[0][ni], 0, 0, 0); \
        acc[1][ni] = __builtin_amdgcn_mfma_f32_16x16x32_bf16(af1, bf, acc[1][ni], 0, 0, 0); \
      }                                                                         \
    }                                                                           \
  }

  float4 areg0, areg1, areg2, areg3;

  // prologue: stage tile 0 (compiler auto-waits areg deps before CVT)
  GLOAD_A(0);
  DMA_B(0, Bs[0]);
  CVT_WRITE_A(0);
  __syncthreads();                    // drains DMA(0) + ds_writes

  for (int it = 0; it < 32; it += 2) {
    // ---- even iter: consumes buffers[0] ----
    GLOAD_A((it + 1) * 64);           // it+1 <= 31 always
    DMA_B((it + 1) * 64, Bs[1]);
    COMPUTE(0);
    CVT_WRITE_A(1);                   // write-late: A(it+1) -> As[1]
    __syncthreads();                  // drains DMA(it+1) + ds_writes; readers of [0] done
    // ---- odd iter: consumes buffers[1] ----
    if (it < 30) {
      GLOAD_A((it + 2) * 64);
      DMA_B((it + 2) * 64, Bs[0]);    // safe: barrier proved Bs[0]/As[0] reads done
      COMPUTE(1);
      CVT_WRITE_A(0);
      __syncthreads();
    } else {
      COMPUTE(1);                     // last tile, nothing to prefetch
    }
  }

  // ---------------- epilogue ----------------
  // b / t of this block's 64 rows (BM divides T_SEQ, so one batch per block)
  const int b  = m0 >> 12;          // m0 / 4096
  const int t0 = m0 & 4095;
  const int dbase2 = (n0 == 192) ? 0 : 32;   // V d-offset of this block's V cols
  ushort* vtile = (ushort*)As;      // reuse As: [96][72] ushort = 13.5 KB <= 16 KB

  __syncthreads();                  // all waves done reading As[1] before reuse

  for (int mi = 0; mi < 2; mi++)
    for (int ni = 0; ni < 3; ni++) {
      int colall = n0 + wn * 48 + ni * 16 + l16;
      int o = colall >> 7, d = colall & 127;
      if (o < 2) {
        ushort* dst = o ? K : Q;
        for (int r = 0; r < 4; r++) {
          int row = m0 + wm * 32 + mi * 16 + quad * 4 + r;
          dst[(size_t)row * D_DIM + d] = f2bf(acc[mi][ni][r]);
        }
      } else {
        int dloc = d - dbase2;      // 0..31 (y==2) or 0..95 (y==3)
        for (int r = 0; r < 4; r++) {
          int mloc = wm * 32 + mi * 16 + quad * 4 + r;
          vtile[dloc * 72 + mloc] = f2bf(acc[mi][ni][r]);
        }
      }
    }

  if (n0 >= 192) {                  // blocks holding V columns write Vt rows
    __syncthreads();                // vtile complete
    const int nrows = (n0 == 192) ? 32 : 96;
    if (tid < nrows * 2) {
      int dloc = tid >> 1, half = tid & 1;
      const ushort* src = vtile + dloc * 72 + half * 32;
      ushort* dstp = Vt + (size_t)(b * D_DIM + dbase2 + dloc) * T_SEQ + t0 + half * 32;
#pragma unroll
      for (int j = 0; j < 4; j++)
        ((uint4*)dstp)[j] = ((const uint4*)src)[j];   // 64 B contiguous per thread
    }
  }
#undef DMA_B
#undef GLOAD_A
#undef CVT_WRITE_A
#undef COMPUTE
}

// ---------------- kernel 3: flash attention partial, fixed-shift softmax ----------------
// grid (qt=64, cq=NCHUNK, b=4). p = exp2(s*scale2 - SHIFT), no running max / rescale;
// row sums via MFMA against all-ones B fragment. Partials are directly summable.
// NEW: NO K/V LDS staging. K and V are L2-resident (1 MB each per batch vs 4 MB/XCD);
// MFMA B-fragments are loaded directly from global at the fragment address (bf16x8,
// 16B-aligned). This removes BOTH per-iteration barriers (Pls is wave-private ->
// DS-ordered without sync), the staging-latency serial path, and the 4.5M staging
// bank conflicts seen in round 7. Waves proceed fully independently.
__global__ __launch_bounds__(256) void attn_partial(const ushort* __restrict__ Q,
                                                    const ushort* __restrict__ K,
                                                    const ushort* __restrict__ Vt,
                                                    ushort* __restrict__ Po,
                                                    float* __restrict__ Ll) {
  const int qt = blockIdx.x, cq = blockIdx.y, b = blockIdx.z;
  const int kt0 = cq * CHUNK_KT;
  if (kt0 > qt) return;

  __shared__ ushort Pls[4][16][72];  // per-wave P [qrow][t] (wave-private slices)

  const int tid = threadIdx.x;
  const int wave = tid >> 6, lane = tid & 63;
  const int quad = lane >> 4, l16 = lane & 15;

  const int qrow = qt * 64 + wave * 16 + l16;
  bf16x8 qf[4];
#pragma unroll
  for (int kk = 0; kk < 4; kk++)
    qf[kk] = *(const bf16x8*)(Q + (size_t)(b * T_SEQ + qrow) * D_DIM + kk * 32 + quad * 8);

  bf16x8 ones;
#pragma unroll
  for (int j = 0; j < 8; j++) ones[j] = (short)0x3F80;  // bf16 1.0

  f32x4 o_acc[8] = {};
  f32x4 lacc = {};
  const float scale2 = 0.08838834764831845f * 1.4426950408889634f;  // 1/sqrt(128)*log2(e)

  const int kt1 = min(qt, kt0 + CHUNK_KT - 1);

  const ushort* Kb  = K  + (size_t)b * T_SEQ * D_DIM;
  const ushort* Vtb = Vt + (size_t)b * D_DIM * T_SEQ;

  for (int kt = kt0; kt <= kt1; kt++) {
    // QK^T: K fragments direct from global (L2-hit), 16 independent loads in flight
    f32x4 s[4] = {};
#pragma unroll
    for (int kk = 0; kk < 4; kk++) {
      const int kc = kk * 32 + quad * 8;
#pragma unroll
      for (int ni = 0; ni < 4; ni++) {
        bf16x8 bf = *(const bf16x8*)(Kb + (size_t)(kt * 64 + ni * 16 + l16) * D_DIM + kc);
        s[ni] = __builtin_amdgcn_mfma_f32_16x16x32_bf16(qf[kk], bf, s[ni], 0, 0, 0);
      }
    }
    // p = exp2(s*scale2 - SHIFT); causal mask only on diagonal tile
    if (kt == qt) {
#pragma unroll
      for (int ni = 0; ni < 4; ni++) {
        int kidx = kt * 64 + ni * 16 + l16;
#pragma unroll
        for (int r = 0; r < 4; r++) {
          int qidx = qt * 64 + wave * 16 + quad * 4 + r;
          float v = (kidx > qidx) ? -1e30f : (s[ni][r] * scale2 - SM_SHIFT);
          s[ni][r] = exp2f(v);
        }
      }
    } else {
#pragma unroll
      for (int ni = 0; ni < 4; ni++)
#pragma unroll
        for (int r = 0; r < 4; r++)
          s[ni][r] = exp2f(s[ni][r] * scale2 - SM_SHIFT);
    }
    // P -> per-wave LDS (C-layout scatter); wave-private, wave-ordered DS ops
#pragma unroll
    for (int ni = 0; ni < 4; ni++)
#pragma unroll
      for (int r = 0; r < 4; r++)
        Pls[wave][quad * 4 + r][ni * 16 + l16] = f2bf(s[ni][r]);
    // PV: V fragments direct from global (L2-hit)
#pragma unroll
    for (int kk2 = 0; kk2 < 2; kk2++) {
      const int kc = kk2 * 32 + quad * 8;
      bf16x8 pf = *(const bf16x8*)(&Pls[wave][l16][kc]);
#pragma unroll
      for (int ni = 0; ni < 8; ni++) {
        bf16x8 vf = *(const bf16x8*)(Vtb + (size_t)(ni * 16 + l16) * T_SEQ + kt * 64 + kc);
        o_acc[ni] = __builtin_amdgcn_mfma_f32_16x16x32_bf16(pf, vf, o_acc[ni], 0, 0, 0);
      }
      lacc = __builtin_amdgcn_mfma_f32_16x16x32_bf16(pf, ones, lacc, 0, 0, 0);  // row sums
    }
  }

  const int slot = (b * 64 + qt) * NCHUNK + cq;
#pragma unroll
  for (int ni = 0; ni < 8; ni++)
#pragma unroll
    for (int r = 0; r < 4; r++) {
      int ql = wave * 16 + quad * 4 + r;
      Po[(size_t)slot * 8192 + ql * D_DIM + ni * 16 + l16] = f2bf(o_acc[ni][r]);
    }
  if (l16 == 0) {
#pragma unroll
    for (int r = 0; r < 4; r++) {
      int ql = wave * 16 + quad * 4 + r;
      Ll[slot * 64 + ql] = lacc[r];
    }
  }
}

// ---------------- kernel 4: split-K reduce (plain sum, fixed shift) ----------------
__global__ __launch_bounds__(256) void attn_reduce(const ushort* __restrict__ Po,
                                                   const float* __restrict__ Ll,
                                                   float* __restrict__ out) {
  const int qt = blockIdx.x, b = blockIdx.y;
  const int nc = qt / CHUNK_KT + 1;
  const int tid = threadIdx.x;
  const int row = tid >> 2;
  const int c0  = (tid & 3) * 32;
  const int base_slot = (b * 64 + qt) * NCHUNK;

  float L = 0.f;
  for (int c = 0; c < nc; c++) L += Ll[(base_slot + c) * 64 + row];
  const float inv = 1.0f / L;

  const size_t orow = (size_t)(b * T_SEQ + qt * 64 + row) * D_DIM;
  for (int cc = 0; cc < 32; cc += 8) {
    float a[8] = {0,0,0,0,0,0,0,0};
    for (int c = 0; c < nc; c++) {
      const ushort* p = Po + (size_t)(base_slot + c) * 8192 + row * D_DIM + c0 + cc;
      ushort u[8];
      *(uint4*)u = *(const uint4*)p;
      for (int j = 0; j < 8; j++) a[j] += bf2f(u[j]);
    }
    float4 o0, o1;
    o0.x = a[0] * inv; o0.y = a[1] * inv; o0.z = a[2] * inv; o0.w = a[3] * inv;
    o1.x = a[4] * inv; o1.y = a[5] * inv; o1.z = a[6] * inv; o1.w = a[7] * inv;
    *(float4*)(out + orow + c0 + cc)     = o0;
    *(float4*)(out + orow + c0 + cc + 4) = o1;
  }
}

extern "C" void kernel_launch(void* const* d_in, const int* in_sizes, int n_in,
                              void* d_out, int out_size, void* d_ws, size_t ws_size,
                              hipStream_t stream) {
  const float* x  = (const float*)d_in[0];
  const float* Wq = (const float*)d_in[1];
  const float* Wk = (const float*)d_in[2];
  const float* Wv = (const float*)d_in[3];
  float* out = (float*)d_out;

  ushort* Q  = (ushort*)d_ws;                       // 16384*128 bf16 each
  ushort* Kb = Q  + (size_t)M_TOT * D_DIM;
  ushort* Vb = Kb + (size_t)M_TOT * D_DIM;          // (slot unused now, kept for layout)
  ushort* Vt = Vb + (size_t)M_TOT * D_DIM;
  ushort* Wt = Vt + (size_t)M_TOT * D_DIM;          // 384*2048 bf16
  ushort* Po = Wt + (size_t)384 * E_DIM;            // (NB*64*NCHUNK) slots * 8192 bf16
  float*  Ll = (float*)(Po + (size_t)NB * 64 * NCHUNK * 8192);

  hipLaunchKernelGGL(build_wt,     dim3(32, 2, 3),       dim3(256), 0, stream, Wq, Wk, Wv, Wt);
  hipLaunchKernelGGL(qkv_gemm,     dim3(256, 4),         dim3(256), 0, stream, x, Wt, Q, Kb, Vt);
  hipLaunchKernelGGL(attn_partial, dim3(64, NCHUNK, 4),  dim3(256), 0, stream, Q, Kb, Vt, Po, Ll);
  hipLaunchKernelGGL(attn_reduce,  dim3(64, 4),          dim3(256), 0, stream, Po, Ll, out);
}

// Round 10
// 306.093 us; speedup vs baseline: 1.3605x; 1.3605x over previous
//
#include <hip/hip_runtime.h>
#include <hip/hip_bf16.h>

typedef short bf16x8 __attribute__((ext_vector_type(8)));
typedef float f32x4  __attribute__((ext_vector_type(4)));

#define T_SEQ 4096
#define NB    4
#define E_DIM 2048
#define D_DIM 128
#define M_TOT (NB * T_SEQ)  // 16384
#define NCHUNK 4
#define CHUNK_KT 16
#define SM_SHIFT 12.0f

__device__ __forceinline__ ushort f2bf(float f) {
  union { float f; unsigned u; } c; c.f = f;
  unsigned u = c.u;
  unsigned r = (u + 0x7FFFu + ((u >> 16) & 1u)) >> 16;  // RNE
  return (ushort)r;
}
__device__ __forceinline__ float bf2f(ushort u) {
  union { unsigned u; float f; } c; c.u = ((unsigned)u) << 16;
  return c.f;
}
// 8 fp32 -> bf16x8 via packed RNE converts
__device__ __forceinline__ bf16x8 cvt8(const float4& lo, const float4& hi) {
  union { __hip_bfloat162 h; ushort u[2]; } t;
  union { ushort u[8]; bf16x8 v; } r;
  t.h = __float22bfloat162_rn(make_float2(lo.x, lo.y)); r.u[0] = t.u[0]; r.u[1] = t.u[1];
  t.h = __float22bfloat162_rn(make_float2(lo.z, lo.w)); r.u[2] = t.u[0]; r.u[3] = t.u[1];
  t.h = __float22bfloat162_rn(make_float2(hi.x, hi.y)); r.u[4] = t.u[0]; r.u[5] = t.u[1];
  t.h = __float22bfloat162_rn(make_float2(hi.z, hi.w)); r.u[6] = t.u[0]; r.u[7] = t.u[1];
  return r.v;
}

// async global -> LDS, 16 bytes per lane; lds dest must be wave-uniform base
__device__ __forceinline__ void gl2lds16(const void* g, void* l) {
  __builtin_amdgcn_global_load_lds(
      (const __attribute__((address_space(1))) unsigned int*)g,
      (__attribute__((address_space(3))) unsigned int*)l, 16, 0, 0);
}

// ---------------- kernel 1: Wt[o*128+n][k] = W_o[k][n]  (bf16, tiled) ----------------
// grid (E/64=32, 128/64=2, 3)
__global__ __launch_bounds__(256) void build_wt(const float* __restrict__ Wq,
                                                const float* __restrict__ Wk,
                                                const float* __restrict__ Wv,
                                                ushort* __restrict__ Wt) {
  __shared__ ushort tile[64][72];   // [k-local][n-local]
  const int tid = threadIdx.x;
  const int k0 = blockIdx.x * 64, n0 = blockIdx.y * 64, o = blockIdx.z;
  const float* W = (o == 0) ? Wq : ((o == 1) ? Wk : Wv);
  for (int i = 0; i < 4; i++) {
    int c = tid + i * 256;
    int r = c >> 4, c4 = (c & 15) * 4;
    float4 v = *(const float4*)(W + (size_t)(k0 + r) * D_DIM + n0 + c4);
    ushort4 b4;
    b4.x = f2bf(v.x); b4.y = f2bf(v.y); b4.z = f2bf(v.z); b4.w = f2bf(v.w);
    *(ushort4*)(&tile[r][c4]) = b4;
  }
  __syncthreads();
  for (int i = 0; i < 2; i++) {
    int c = tid + i * 256;
    int nn = c >> 3, k8 = (c & 7) * 8;
    ushort tmp[8];
    for (int j = 0; j < 8; j++) tmp[j] = tile[k8 + j][nn];
    *(uint4*)(Wt + (size_t)((o << 7) + n0 + nn) * E_DIM + k0 + k8) = *(const uint4*)tmp;
  }
}

// ---------------- kernel 2: QKV GEMM + fused V-transpose epilogue ----------------
// ROUND-5 core (best measured: 92.4 us, occ 38%, VGPR 52). BM=64, BN=96, BK=64;
// grid (256,4) = 1024 blocks = 4/CU (LDS 40KB).
__global__ __launch_bounds__(256, 4) void qkv_gemm(const float* __restrict__ x,
                                                   const ushort* __restrict__ Wt,
                                                   ushort* __restrict__ Q,
                                                   ushort* __restrict__ K,
                                                   ushort* __restrict__ Vt) {
  __shared__ ushort As[2][64 * 64];   // [m][k] bf16, swizzled 16B groups (16 KB)
  __shared__ ushort Bs[2][96 * 64];   // [n][k] bf16, swizzled 16B groups (24 KB)

  const int tid  = threadIdx.x;
  const int wave = tid >> 6, lane = tid & 63;
  const int quad = lane >> 4, l16 = lane & 15;
  const int wm = wave >> 1, wn = wave & 1;   // 2x2 waves, wave tile 32x48
  const int m0 = blockIdx.x * 64;
  const int n0 = blockIdx.y * 96;

  f32x4 acc[2][3] = {};

  // B DMA slot geometry: slot s (16B) holds row n = s>>3; physical group p = s&7
  // stores logical col-group cg = p ^ (n&7)
  const int s_ = wave * 64 + lane;
  const int n_ = s_ >> 3, p_ = s_ & 7;

  // A staging geometry: thread t owns row r = t>>2, k-quarter q4 = t&3 (16 floats)
  const int ar_ = tid >> 2, aq4_ = tid & 3;
  const float* xrow = x + (size_t)(m0 + ar_) * E_DIM + aq4_ * 16;

#define DMA_B(k0_, buf_)                                                        \
  _Pragma("unroll")                                                             \
  for (int i_ = 0; i_ < 3; i_++) {                                              \
    int slotbase = i_ * 256 + wave * 64;                                        \
    int n = (i_ * 32) + n_;            /* = (slotbase+lane)>>3 */               \
    int cg = p_ ^ (n & 7);                                                      \
    gl2lds16(Wt + (size_t)(n0 + n) * E_DIM + (k0_) + cg * 8,                    \
             (char*)(buf_) + (size_t)slotbase * 16);                            \
  }

#define GLOAD_A(k0_)                                                            \
  {                                                                             \
    const float* ap_ = xrow + (k0_);                                            \
    areg0 = *(const float4*)(ap_);                                              \
    areg1 = *(const float4*)(ap_ + 4);                                          \
    areg2 = *(const float4*)(ap_ + 8);                                          \
    areg3 = *(const float4*)(ap_ + 12);                                         \
  }

#define CVT_WRITE_A(bufidx)                                                     \
  {                                                                             \
    ushort* as_ = As[bufidx];                                                   \
    bf16x8 w0_ = cvt8(areg0, areg1);                                            \
    bf16x8 w1_ = cvt8(areg2, areg3);                                            \
    *(bf16x8*)(as_ + ar_ * 64 + (((aq4_ * 2)     ^ (ar_ & 7)) * 8)) = w0_;      \
    *(bf16x8*)(as_ + ar_ * 64 + (((aq4_ * 2 + 1) ^ (ar_ & 7)) * 8)) = w1_;      \
  }

#define COMPUTE(bufidx)                                                         \
  {                                                                             \
    const ushort* as_ = As[bufidx];                                             \
    const ushort* bs_ = Bs[bufidx];                                             \
    _Pragma("unroll")                                                           \
    for (int kk = 0; kk < 2; kk++) {                                            \
      const int slot = ((kk * 4 + quad) ^ (l16 & 7)) * 8;                       \
      bf16x8 af0 = *(const bf16x8*)(as_ + (wm * 32 + l16) * 64 + slot);         \
      bf16x8 af1 = *(const bf16x8*)(as_ + (wm * 32 + 16 + l16) * 64 + slot);    \
      _Pragma("unroll")                                                         \
      for (int ni = 0; ni < 3; ni++) {                                          \
        int n = wn * 48 + ni * 16 + l16;                                        \
        bf16x8 bf = *(const bf16x8*)(bs_ + n * 64 + slot);                      \
        acc[0][ni] = __builtin_amdgcn_mfma_f32_16x16x32_bf16(af0, bf, acc[0][ni], 0, 0, 0); \
        acc[1][ni] = __builtin_amdgcn_mfma_f32_16x16x32_bf16(af1, bf, acc[1][ni], 0, 0, 0); \
      }                                                                         \
    }                                                                           \
  }

  float4 areg0, areg1, areg2, areg3;

  // prologue: stage tile 0 (compiler auto-waits areg deps before CVT)
  GLOAD_A(0);
  DMA_B(0, Bs[0]);
  CVT_WRITE_A(0);
  __syncthreads();                    // drains DMA(0) + ds_writes

  for (int it = 0; it < 32; it += 2) {
    // ---- even iter: consumes buffers[0] ----
    GLOAD_A((it + 1) * 64);           // it+1 <= 31 always
    DMA_B((it + 1) * 64, Bs[1]);
    COMPUTE(0);
    CVT_WRITE_A(1);                   // write-late: A(it+1) -> As[1]
    __syncthreads();                  // drains DMA(it+1) + ds_writes; readers of [0] done
    // ---- odd iter: consumes buffers[1] ----
    if (it < 30) {
      GLOAD_A((it + 2) * 64);
      DMA_B((it + 2) * 64, Bs[0]);    // safe: barrier proved Bs[0]/As[0] reads done
      COMPUTE(1);
      CVT_WRITE_A(0);
      __syncthreads();
    } else {
      COMPUTE(1);                     // last tile, nothing to prefetch
    }
  }

  // ---------------- epilogue ----------------
  // b / t of this block's 64 rows (BM divides T_SEQ, so one batch per block)
  const int b  = m0 >> 12;          // m0 / 4096
  const int t0 = m0 & 4095;
  const int dbase2 = (n0 == 192) ? 0 : 32;   // V d-offset of this block's V cols
  ushort* vtile = (ushort*)As;      // reuse As: [96][72] ushort = 13.5 KB <= 16 KB

  __syncthreads();                  // all waves done reading As[1] before reuse

  for (int mi = 0; mi < 2; mi++)
    for (int ni = 0; ni < 3; ni++) {
      int colall = n0 + wn * 48 + ni * 16 + l16;
      int o = colall >> 7, d = colall & 127;
      if (o < 2) {
        ushort* dst = o ? K : Q;
        for (int r = 0; r < 4; r++) {
          int row = m0 + wm * 32 + mi * 16 + quad * 4 + r;
          dst[(size_t)row * D_DIM + d] = f2bf(acc[mi][ni][r]);
        }
      } else {
        int dloc = d - dbase2;      // 0..31 (y==2) or 0..95 (y==3)
        for (int r = 0; r < 4; r++) {
          int mloc = wm * 32 + mi * 16 + quad * 4 + r;
          vtile[dloc * 72 + mloc] = f2bf(acc[mi][ni][r]);
        }
      }
    }

  if (n0 >= 192) {                  // blocks holding V columns write Vt rows
    __syncthreads();                // vtile complete
    const int nrows = (n0 == 192) ? 32 : 96;
    if (tid < nrows * 2) {
      int dloc = tid >> 1, half = tid & 1;
      const ushort* src = vtile + dloc * 72 + half * 32;
      ushort* dstp = Vt + (size_t)(b * D_DIM + dbase2 + dloc) * T_SEQ + t0 + half * 32;
#pragma unroll
      for (int j = 0; j < 4; j++)
        ((uint4*)dstp)[j] = ((const uint4*)src)[j];   // 64 B contiguous per thread
    }
  }
#undef DMA_B
#undef GLOAD_A
#undef CVT_WRITE_A
#undef COMPUTE
}

// ---------------- kernel 3: flash attention partial, fixed-shift softmax ----------------
// grid (qt=64, cq=NCHUNK, b=4). p = exp2(s*scale2 - SHIFT), no running max / rescale;
// row sums via MFMA against all-ones B fragment. Partials are directly summable.
// NEW staging: async DMA double-buffer (qkv-style). K/V(kt+1) staged via
// global_load_lds (zero VGPRs -> no round-7 spill) into XOR-swizzled UNPADDED tiles
// (DMA needs linear dest; swizzle applied on the GLOBAL source, rule #21) while
// tile kt computes; ONE barrier per iteration drains the DMA. Removes the exposed
// staging latency, the second barrier, and the staging bank conflicts.
// K tile [64][128]: slot s -> row n=s>>4, phys grp p=s&15 holds logical cg=p^(n&7).
// V tile [128][64]: slot s -> row d=s>>3, phys grp p=s&7  holds logical cg=p^(d&7).
// Reads use grp g^(row&7): 16 lanes -> 8 windows x2 = 2-way (free).
// LDS 73.25KB -> 2 blocks/CU.
__global__ __launch_bounds__(256, 2) void attn_partial(const ushort* __restrict__ Q,
                                                       const ushort* __restrict__ K,
                                                       const ushort* __restrict__ Vt,
                                                       ushort* __restrict__ Po,
                                                       float* __restrict__ Ll) {
  const int qt = blockIdx.x, cq = blockIdx.y, b = blockIdx.z;
  const int kt0 = cq * CHUNK_KT;
  if (kt0 > qt) return;

  __shared__ ushort Kt[2][64 * 128];   // 32 KB, swizzled 16B groups
  __shared__ ushort Vts[2][128 * 64];  // 32 KB, swizzled 16B groups
  __shared__ ushort Pls[4][16][72];    // per-wave P [qrow][t] (wave-private)

  const int tid = threadIdx.x;
  const int wave = tid >> 6, lane = tid & 63;
  const int quad = lane >> 4, l16 = lane & 15;

  const ushort* Kb  = K  + (size_t)b * T_SEQ * D_DIM;
  const ushort* Vtb = Vt + (size_t)b * D_DIM * T_SEQ;

  // DMA geometry (per thread): K slot sk = i*256 + tid; V slot sv likewise.
  const int skn_ = tid >> 4, skp_ = tid & 15;   // within 256-slot group: row step 16/issue
  const int svd_ = tid >> 3, svp_ = tid & 7;    // V: row step 32/issue

#define DMA_K(kt_, buf_)                                                        \
  _Pragma("unroll")                                                             \
  for (int i_ = 0; i_ < 4; i_++) {                                              \
    int slotbase = i_ * 256 + wave * 64;                                        \
    int n = i_ * 16 + skn_;                                                     \
    int cg = skp_ ^ (n & 7);                                                    \
    gl2lds16(Kb + (size_t)((kt_) * 64 + n) * D_DIM + cg * 8,                    \
             (char*)(Kt[buf_]) + (size_t)slotbase * 16);                        \
  }

#define DMA_V(kt_, buf_)                                                        \
  _Pragma("unroll")                                                             \
  for (int i_ = 0; i_ < 4; i_++) {                                              \
    int slotbase = i_ * 256 + wave * 64;                                        \
    int d = i_ * 32 + svd_;                                                     \
    int cg = svp_ ^ (d & 7);                                                    \
    gl2lds16(Vtb + (size_t)d * T_SEQ + (kt_) * 64 + cg * 8,                     \
             (char*)(Vts[buf_]) + (size_t)slotbase * 16);                       \
  }

  const int qrow = qt * 64 + wave * 16 + l16;
  bf16x8 qf[4];
#pragma unroll
  for (int kk = 0; kk < 4; kk++)
    qf[kk] = *(const bf16x8*)(Q + (size_t)(b * T_SEQ + qrow) * D_DIM + kk * 32 + quad * 8);

  bf16x8 ones;
#pragma unroll
  for (int j = 0; j < 8; j++) ones[j] = (short)0x3F80;  // bf16 1.0

  f32x4 o_acc[8] = {};
  f32x4 lacc = {};
  const float scale2 = 0.08838834764831845f * 1.4426950408889634f;  // 1/sqrt(128)*log2(e)

  const int kt1 = min(qt, kt0 + CHUNK_KT - 1);

  // prologue: stage tile kt0 (latency exposed once per block)
  DMA_K(kt0, 0);
  DMA_V(kt0, 0);
  __syncthreads();

  for (int kt = kt0; kt <= kt1; kt++) {
    const int cur = (kt - kt0) & 1;
    if (kt < kt1) { DMA_K(kt + 1, cur ^ 1); DMA_V(kt + 1, cur ^ 1); }  // async, in flight
    const ushort* kts = Kt[cur];
    const ushort* vts = Vts[cur];

    // QK^T from swizzled LDS
    f32x4 s[4] = {};
#pragma unroll
    for (int kk = 0; kk < 4; kk++) {
#pragma unroll
      for (int ni = 0; ni < 4; ni++) {
        int row = ni * 16 + l16;
        int pg = (kk * 4 + quad) ^ (row & 7);
        bf16x8 bf = *(const bf16x8*)(kts + row * 128 + pg * 8);
        s[ni] = __builtin_amdgcn_mfma_f32_16x16x32_bf16(qf[kk], bf, s[ni], 0, 0, 0);
      }
    }
    // p = exp2(s*scale2 - SHIFT); causal mask only on diagonal tile
    if (kt == qt) {
#pragma unroll
      for (int ni = 0; ni < 4; ni++) {
        int kidx = kt * 64 + ni * 16 + l16;
#pragma unroll
        for (int r = 0; r < 4; r++) {
          int qidx = qt * 64 + wave * 16 + quad * 4 + r;
          float v = (kidx > qidx) ? -1e30f : (s[ni][r] * scale2 - SM_SHIFT);
          s[ni][r] = exp2f(v);
        }
      }
    } else {
#pragma unroll
      for (int ni = 0; ni < 4; ni++)
#pragma unroll
        for (int r = 0; r < 4; r++)
          s[ni][r] = exp2f(s[ni][r] * scale2 - SM_SHIFT);
    }
    // P -> per-wave LDS (C-layout scatter); wave-private, wave-ordered DS ops
#pragma unroll
    for (int ni = 0; ni < 4; ni++)
#pragma unroll
      for (int r = 0; r < 4; r++)
        Pls[wave][quad * 4 + r][ni * 16 + l16] = f2bf(s[ni][r]);
    // PV from swizzled LDS
#pragma unroll
    for (int kk2 = 0; kk2 < 2; kk2++) {
      const int kc = kk2 * 32 + quad * 8;
      bf16x8 pf = *(const bf16x8*)(&Pls[wave][l16][kc]);
#pragma unroll
      for (int ni = 0; ni < 8; ni++) {
        int row = ni * 16 + l16;
        int pg = (kk2 * 4 + quad) ^ (row & 7);
        bf16x8 vf = *(const bf16x8*)(vts + row * 64 + pg * 8);
        o_acc[ni] = __builtin_amdgcn_mfma_f32_16x16x32_bf16(pf, vf, o_acc[ni], 0, 0, 0);
      }
      lacc = __builtin_amdgcn_mfma_f32_16x16x32_bf16(pf, ones, lacc, 0, 0, 0);  // row sums
    }

    __syncthreads();   // drains DMA(kt+1) (vmcnt 0) + all waves done reading cur bufs
  }

  const int slot = (b * 64 + qt) * NCHUNK + cq;
#pragma unroll
  for (int ni = 0; ni < 8; ni++)
#pragma unroll
    for (int r = 0; r < 4; r++) {
      int ql = wave * 16 + quad * 4 + r;
      Po[(size_t)slot * 8192 + ql * D_DIM + ni * 16 + l16] = f2bf(o_acc[ni][r]);
    }
  if (l16 == 0) {
#pragma unroll
    for (int r = 0; r < 4; r++) {
      int ql = wave * 16 + quad * 4 + r;
      Ll[slot * 64 + ql] = lacc[r];
    }
  }
#undef DMA_K
#undef DMA_V
}

// ---------------- kernel 4: split-K reduce (plain sum, fixed shift) ----------------
__global__ __launch_bounds__(256) void attn_reduce(const ushort* __restrict__ Po,
                                                   const float* __restrict__ Ll,
                                                   float* __restrict__ out) {
  const int qt = blockIdx.x, b = blockIdx.y;
  const int nc = qt / CHUNK_KT + 1;
  const int tid = threadIdx.x;
  const int row = tid >> 2;
  const int c0  = (tid & 3) * 32;
  const int base_slot = (b * 64 + qt) * NCHUNK;

  float L = 0.f;
  for (int c = 0; c < nc; c++) L += Ll[(base_slot + c) * 64 + row];
  const float inv = 1.0f / L;

  const size_t orow = (size_t)(b * T_SEQ + qt * 64 + row) * D_DIM;
  for (int cc = 0; cc < 32; cc += 8) {
    float a[8] = {0,0,0,0,0,0,0,0};
    for (int c = 0; c < nc; c++) {
      const ushort* p = Po + (size_t)(base_slot + c) * 8192 + row * D_DIM + c0 + cc;
      ushort u[8];
      *(uint4*)u = *(const uint4*)p;
      for (int j = 0; j < 8; j++) a[j] += bf2f(u[j]);
    }
    float4 o0, o1;
    o0.x = a[0] * inv; o0.y = a[1] * inv; o0.z = a[2] * inv; o0.w = a[3] * inv;
    o1.x = a[4] * inv; o1.y = a[5] * inv; o1.z = a[6] * inv; o1.w = a[7] * inv;
    *(float4*)(out + orow + c0 + cc)     = o0;
    *(float4*)(out + orow + c0 + cc + 4) = o1;
  }
}

extern "C" void kernel_launch(void* const* d_in, const int* in_sizes, int n_in,
                              void* d_out, int out_size, void* d_ws, size_t ws_size,
                              hipStream_t stream) {
  const float* x  = (const float*)d_in[0];
  const float* Wq = (const float*)d_in[1];
  const float* Wk = (const float*)d_in[2];
  const float* Wv = (const float*)d_in[3];
  float* out = (float*)d_out;

  ushort* Q  = (ushort*)d_ws;                       // 16384*128 bf16 each
  ushort* Kb = Q  + (size_t)M_TOT * D_DIM;
  ushort* Vb = Kb + (size_t)M_TOT * D_DIM;          // (slot unused now, kept for layout)
  ushort* Vt = Vb + (size_t)M_TOT * D_DIM;
  ushort* Wt = Vt + (size_t)M_TOT * D_DIM;          // 384*2048 bf16
  ushort* Po = Wt + (size_t)384 * E_DIM;            // (NB*64*NCHUNK) slots * 8192 bf16
  float*  Ll = (float*)(Po + (size_t)NB * 64 * NCHUNK * 8192);

  hipLaunchKernelGGL(build_wt,     dim3(32, 2, 3),       dim3(256), 0, stream, Wq, Wk, Wv, Wt);
  hipLaunchKernelGGL(qkv_gemm,     dim3(256, 4),         dim3(256), 0, stream, x, Wt, Q, Kb, Vt);
  hipLaunchKernelGGL(attn_partial, dim3(64, NCHUNK, 4),  dim3(256), 0, stream, Q, Kb, Vt, Po, Ll);
  hipLaunchKernelGGL(attn_reduce,  dim3(64, 4),          dim3(256), 0, stream, Po, Ll, out);
}

// Round 11
// 302.730 us; speedup vs baseline: 1.3756x; 1.0111x over previous
//
#include <hip/hip_runtime.h>
#include <hip/hip_bf16.h>

typedef short bf16x8 __attribute__((ext_vector_type(8)));
typedef float f32x4  __attribute__((ext_vector_type(4)));

#define T_SEQ 4096
#define NB    4
#define E_DIM 2048
#define D_DIM 128
#define M_TOT (NB * T_SEQ)  // 16384
#define NCHUNK 4
#define CHUNK_KT 16
#define SM_SHIFT 12.0f

__device__ __forceinline__ ushort f2bf(float f) {
  union { float f; unsigned u; } c; c.f = f;
  unsigned u = c.u;
  unsigned r = (u + 0x7FFFu + ((u >> 16) & 1u)) >> 16;  // RNE
  return (ushort)r;
}
__device__ __forceinline__ float bf2f(ushort u) {
  union { unsigned u; float f; } c; c.u = ((unsigned)u) << 16;
  return c.f;
}
// 8 fp32 -> bf16x8 via packed RNE converts
__device__ __forceinline__ bf16x8 cvt8(const float4& lo, const float4& hi) {
  union { __hip_bfloat162 h; ushort u[2]; } t;
  union { ushort u[8]; bf16x8 v; } r;
  t.h = __float22bfloat162_rn(make_float2(lo.x, lo.y)); r.u[0] = t.u[0]; r.u[1] = t.u[1];
  t.h = __float22bfloat162_rn(make_float2(lo.z, lo.w)); r.u[2] = t.u[0]; r.u[3] = t.u[1];
  t.h = __float22bfloat162_rn(make_float2(hi.x, hi.y)); r.u[4] = t.u[0]; r.u[5] = t.u[1];
  t.h = __float22bfloat162_rn(make_float2(hi.z, hi.w)); r.u[6] = t.u[0]; r.u[7] = t.u[1];
  return r.v;
}

// async global -> LDS, 16 bytes per lane; lds dest must be wave-uniform base
__device__ __forceinline__ void gl2lds16(const void* g, void* l) {
  __builtin_amdgcn_global_load_lds(
      (const __attribute__((address_space(1))) unsigned int*)g,
      (__attribute__((address_space(3))) unsigned int*)l, 16, 0, 0);
}

// ---------------- kernel 1: Wt[o*128+n][k] = W_o[k][n]  (bf16, tiled) ----------------
// grid (E/64=32, 128/64=2, 3)
__global__ __launch_bounds__(256) void build_wt(const float* __restrict__ Wq,
                                                const float* __restrict__ Wk,
                                                const float* __restrict__ Wv,
                                                ushort* __restrict__ Wt) {
  __shared__ ushort tile[64][72];   // [k-local][n-local]
  const int tid = threadIdx.x;
  const int k0 = blockIdx.x * 64, n0 = blockIdx.y * 64, o = blockIdx.z;
  const float* W = (o == 0) ? Wq : ((o == 1) ? Wk : Wv);
  for (int i = 0; i < 4; i++) {
    int c = tid + i * 256;
    int r = c >> 4, c4 = (c & 15) * 4;
    float4 v = *(const float4*)(W + (size_t)(k0 + r) * D_DIM + n0 + c4);
    ushort4 b4;
    b4.x = f2bf(v.x); b4.y = f2bf(v.y); b4.z = f2bf(v.z); b4.w = f2bf(v.w);
    *(ushort4*)(&tile[r][c4]) = b4;
  }
  __syncthreads();
  for (int i = 0; i < 2; i++) {
    int c = tid + i * 256;
    int nn = c >> 3, k8 = (c & 7) * 8;
    ushort tmp[8];
    for (int j = 0; j < 8; j++) tmp[j] = tile[k8 + j][nn];
    *(uint4*)(Wt + (size_t)((o << 7) + n0 + nn) * E_DIM + k0 + k8) = *(const uint4*)tmp;
  }
}

// ---------------- kernel 1b: x (fp32) -> xbf (bf16), streaming ----------------
__global__ __launch_bounds__(256) void x_cvt(const float* __restrict__ x,
                                             ushort* __restrict__ xbf) {
  const size_t n8 = (size_t)M_TOT * E_DIM / 8;
  const size_t stride = (size_t)gridDim.x * 256;
  for (size_t i = (size_t)blockIdx.x * 256 + threadIdx.x; i < n8; i += stride) {
    const float* p = x + i * 8;
    float4 lo = *(const float4*)p;
    float4 hi = *(const float4*)(p + 4);
    *(bf16x8*)(xbf + i * 8) = cvt8(lo, hi);
  }
}

// ---------------- kernel 2: QKV GEMM (bf16 A via DMA) + fused V-transpose ----------------
// m97 structure: BOTH operands via global_load_lds (zero VGPR staging), BM=64,
// BN=96, BK=64, grid (256,4), LDS 40KB -> 4 blocks/CU. Swizzle: phys 16B-group p
// of row r holds logical group p^(r&7); DMA source pre-swizzled, reads XOR back.
__global__ __launch_bounds__(256, 4) void qkv_gemm_bf(const ushort* __restrict__ xbf,
                                                      const ushort* __restrict__ Wt,
                                                      ushort* __restrict__ Q,
                                                      ushort* __restrict__ K,
                                                      ushort* __restrict__ Vt) {
  __shared__ ushort As[2][64 * 64];   // [m][k] bf16, swizzled (16 KB)
  __shared__ ushort Bs[2][96 * 64];   // [n][k] bf16, swizzled (24 KB)

  const int tid  = threadIdx.x;
  const int wave = tid >> 6, lane = tid & 63;
  const int quad = lane >> 4, l16 = lane & 15;
  const int wm = wave >> 1, wn = wave & 1;   // 2x2 waves, wave tile 32x48
  const int m0 = blockIdx.x * 64;
  const int n0 = blockIdx.y * 96;

  f32x4 acc[2][3] = {};

  const int s_ = wave * 64 + lane;
  const int n_ = s_ >> 3, p_ = s_ & 7;          // B: row n=s>>3, phys grp s&7
  const int arow_ = wave * 8 + (lane >> 3);     // A: row within 32-row slab
  const int ap_ = lane & 7;

#define DMA_B(k0_, buf_)                                                        \
  _Pragma("unroll")                                                             \
  for (int i_ = 0; i_ < 3; i_++) {                                              \
    int slotbase = i_ * 256 + wave * 64;                                        \
    int n = (i_ * 32) + n_;                                                     \
    int cg = p_ ^ (n & 7);                                                      \
    gl2lds16(Wt + (size_t)(n0 + n) * E_DIM + (k0_) + cg * 8,                    \
             (char*)(buf_) + (size_t)slotbase * 16);                            \
  }

#define DMA_A(k0_, buf_)                                                        \
  _Pragma("unroll")                                                             \
  for (int i_ = 0; i_ < 2; i_++) {                                              \
    int slotbase = i_ * 256 + wave * 64;                                        \
    int row = i_ * 32 + arow_;                                                  \
    int cg = ap_ ^ (row & 7);                                                   \
    gl2lds16(xbf + (size_t)(m0 + row) * E_DIM + (k0_) + cg * 8,                 \
             (char*)(buf_) + (size_t)slotbase * 16);                            \
  }

#define COMPUTE(bufidx)                                                         \
  {                                                                             \
    const ushort* as_ = As[bufidx];                                             \
    const ushort* bs_ = Bs[bufidx];                                             \
    _Pragma("unroll")                                                           \
    for (int kk = 0; kk < 2; kk++) {                                            \
      const int slot = ((kk * 4 + quad) ^ (l16 & 7)) * 8;                       \
      bf16x8 af0 = *(const bf16x8*)(as_ + (wm * 32 + l16) * 64 + slot);         \
      bf16x8 af1 = *(const bf16x8*)(as_ + (wm * 32 + 16 + l16) * 64 + slot);    \
      _Pragma("unroll")                                                         \
      for (int ni = 0; ni < 3; ni++) {                                          \
        int n = wn * 48 + ni * 16 + l16;                                        \
        bf16x8 bf = *(const bf16x8*)(bs_ + n * 64 + slot);                      \
        acc[0][ni] = __builtin_amdgcn_mfma_f32_16x16x32_bf16(af0, bf, acc[0][ni], 0, 0, 0); \
        acc[1][ni] = __builtin_amdgcn_mfma_f32_16x16x32_bf16(af1, bf, acc[1][ni], 0, 0, 0); \
      }                                                                         \
    }                                                                           \
  }

  DMA_A(0, As[0]);
  DMA_B(0, Bs[0]);
  __syncthreads();

  for (int it = 0; it < 32; it++) {
    if (it < 31) {
      DMA_A((it + 1) * 64, As[(it + 1) & 1]);
      DMA_B((it + 1) * 64, Bs[(it + 1) & 1]);
    }
    COMPUTE(it & 1);
    __syncthreads();   // drains DMA(it+1); all waves done reading buf[it&1]
  }

  // ---------------- epilogue (fused V transpose) ----------------
  const int b  = m0 >> 12;
  const int t0 = m0 & 4095;
  const int dbase2 = (n0 == 192) ? 0 : 32;
  ushort* vtile = (ushort*)As;      // reuse As: [96][72] ushort

  __syncthreads();

  for (int mi = 0; mi < 2; mi++)
    for (int ni = 0; ni < 3; ni++) {
      int colall = n0 + wn * 48 + ni * 16 + l16;
      int o = colall >> 7, d = colall & 127;
      if (o < 2) {
        ushort* dst = o ? K : Q;
        for (int r = 0; r < 4; r++) {
          int row = m0 + wm * 32 + mi * 16 + quad * 4 + r;
          dst[(size_t)row * D_DIM + d] = f2bf(acc[mi][ni][r]);
        }
      } else {
        int dloc = d - dbase2;
        for (int r = 0; r < 4; r++) {
          int mloc = wm * 32 + mi * 16 + quad * 4 + r;
          vtile[dloc * 72 + mloc] = f2bf(acc[mi][ni][r]);
        }
      }
    }

  if (n0 >= 192) {
    __syncthreads();
    const int nrows = (n0 == 192) ? 32 : 96;
    if (tid < nrows * 2) {
      int dloc = tid >> 1, half = tid & 1;
      const ushort* src = vtile + dloc * 72 + half * 32;
      ushort* dstp = Vt + (size_t)(b * D_DIM + dbase2 + dloc) * T_SEQ + t0 + half * 32;
#pragma unroll
      for (int j = 0; j < 4; j++)
        ((uint4*)dstp)[j] = ((const uint4*)src)[j];
    }
  }
#undef DMA_B
#undef DMA_A
#undef COMPUTE
}

// ---------------- kernel 2-alt: round-8 fp32-A qkv (ws fallback) ----------------
__global__ __launch_bounds__(256, 4) void qkv_gemm(const float* __restrict__ x,
                                                   const ushort* __restrict__ Wt,
                                                   ushort* __restrict__ Q,
                                                   ushort* __restrict__ K,
                                                   ushort* __restrict__ Vt) {
  __shared__ ushort As[2][64 * 64];
  __shared__ ushort Bs[2][96 * 64];

  const int tid  = threadIdx.x;
  const int wave = tid >> 6, lane = tid & 63;
  const int quad = lane >> 4, l16 = lane & 15;
  const int wm = wave >> 1, wn = wave & 1;
  const int m0 = blockIdx.x * 64;
  const int n0 = blockIdx.y * 96;

  f32x4 acc[2][3] = {};

  const int s_ = wave * 64 + lane;
  const int n_ = s_ >> 3, p_ = s_ & 7;
  const int ar_ = tid >> 2, aq4_ = tid & 3;
  const float* xrow = x + (size_t)(m0 + ar_) * E_DIM + aq4_ * 16;

#define DMA_B(k0_, buf_)                                                        \
  _Pragma("unroll")                                                             \
  for (int i_ = 0; i_ < 3; i_++) {                                              \
    int slotbase = i_ * 256 + wave * 64;                                        \
    int n = (i_ * 32) + n_;                                                     \
    int cg = p_ ^ (n & 7);                                                      \
    gl2lds16(Wt + (size_t)(n0 + n) * E_DIM + (k0_) + cg * 8,                    \
             (char*)(buf_) + (size_t)slotbase * 16);                            \
  }

#define GLOAD_A(k0_)                                                            \
  {                                                                             \
    const float* ap_ = xrow + (k0_);                                            \
    areg0 = *(const float4*)(ap_);                                              \
    areg1 = *(const float4*)(ap_ + 4);                                          \
    areg2 = *(const float4*)(ap_ + 8);                                          \
    areg3 = *(const float4*)(ap_ + 12);                                         \
  }

#define CVT_WRITE_A(bufidx)                                                     \
  {                                                                             \
    ushort* as_ = As[bufidx];                                                   \
    bf16x8 w0_ = cvt8(areg0, areg1);                                            \
    bf16x8 w1_ = cvt8(areg2, areg3);                                            \
    *(bf16x8*)(as_ + ar_ * 64 + (((aq4_ * 2)     ^ (ar_ & 7)) * 8)) = w0_;      \
    *(bf16x8*)(as_ + ar_ * 64 + (((aq4_ * 2 + 1) ^ (ar_ & 7)) * 8)) = w1_;      \
  }

#define COMPUTE(bufidx)                                                         \
  {                                                                             \
    const ushort* as_ = As[bufidx];                                             \
    const ushort* bs_ = Bs[bufidx];                                             \
    _Pragma("unroll")                                                           \
    for (int kk = 0; kk < 2; kk++) {                                            \
      const int slot = ((kk * 4 + quad) ^ (l16 & 7)) * 8;                       \
      bf16x8 af0 = *(const bf16x8*)(as_ + (wm * 32 + l16) * 64 + slot);         \
      bf16x8 af1 = *(const bf16x8*)(as_ + (wm * 32 + 16 + l16) * 64 + slot);    \
      _Pragma("unroll")                                                         \
      for (int ni = 0; ni < 3; ni++) {                                          \
        int n = wn * 48 + ni * 16 + l16;                                        \
        bf16x8 bf = *(const bf16x8*)(bs_ + n * 64 + slot);                      \
        acc[0][ni] = __builtin_amdgcn_mfma_f32_16x16x32_bf16(af0, bf, acc[0][ni], 0, 0, 0); \
        acc[1][ni] = __builtin_amdgcn_mfma_f32_16x16x32_bf16(af1, bf, acc[1][ni], 0, 0, 0); \
      }                                                                         \
    }                                                                           \
  }

  float4 areg0, areg1, areg2, areg3;

  GLOAD_A(0);
  DMA_B(0, Bs[0]);
  CVT_WRITE_A(0);
  __syncthreads();

  for (int it = 0; it < 32; it += 2) {
    GLOAD_A((it + 1) * 64);
    DMA_B((it + 1) * 64, Bs[1]);
    COMPUTE(0);
    CVT_WRITE_A(1);
    __syncthreads();
    if (it < 30) {
      GLOAD_A((it + 2) * 64);
      DMA_B((it + 2) * 64, Bs[0]);
      COMPUTE(1);
      CVT_WRITE_A(0);
      __syncthreads();
    } else {
      COMPUTE(1);
    }
  }

  const int b  = m0 >> 12;
  const int t0 = m0 & 4095;
  const int dbase2 = (n0 == 192) ? 0 : 32;
  ushort* vtile = (ushort*)As;

  __syncthreads();

  for (int mi = 0; mi < 2; mi++)
    for (int ni = 0; ni < 3; ni++) {
      int colall = n0 + wn * 48 + ni * 16 + l16;
      int o = colall >> 7, d = colall & 127;
      if (o < 2) {
        ushort* dst = o ? K : Q;
        for (int r = 0; r < 4; r++) {
          int row = m0 + wm * 32 + mi * 16 + quad * 4 + r;
          dst[(size_t)row * D_DIM + d] = f2bf(acc[mi][ni][r]);
        }
      } else {
        int dloc = d - dbase2;
        for (int r = 0; r < 4; r++) {
          int mloc = wm * 32 + mi * 16 + quad * 4 + r;
          vtile[dloc * 72 + mloc] = f2bf(acc[mi][ni][r]);
        }
      }
    }

  if (n0 >= 192) {
    __syncthreads();
    const int nrows = (n0 == 192) ? 32 : 96;
    if (tid < nrows * 2) {
      int dloc = tid >> 1, half = tid & 1;
      const ushort* src = vtile + dloc * 72 + half * 32;
      ushort* dstp = Vt + (size_t)(b * D_DIM + dbase2 + dloc) * T_SEQ + t0 + half * 32;
#pragma unroll
      for (int j = 0; j < 4; j++)
        ((uint4*)dstp)[j] = ((const uint4*)src)[j];
    }
  }
#undef DMA_B
#undef GLOAD_A
#undef CVT_WRITE_A
#undef COMPUTE
}

// ---------------- kernel 3: flash attention partial, fixed-shift softmax ----------------
// Single-buffered swizzled DMA staging at EXACTLY 40KB LDS -> 4 blocks/CU (the
// occupancy lever; round-10's 2-buf 73KB/2-blocks regressed). Per tile:
// barrier (readers done) -> DMA K/V (zero-VGPR) -> barrier (vmcnt drain) -> compute.
// Swizzle (validated round 10): phys 16B-group p of row r holds logical p^(r&7).
__global__ __launch_bounds__(256, 4) void attn_partial(const ushort* __restrict__ Q,
                                                       const ushort* __restrict__ K,
                                                       const ushort* __restrict__ Vt,
                                                       ushort* __restrict__ Po,
                                                       float* __restrict__ Ll) {
  const int qt = blockIdx.x, cq = blockIdx.y, b = blockIdx.z;
  const int kt0 = cq * CHUNK_KT;
  if (kt0 > qt) return;

  __shared__ ushort Kt[64 * 128];    // 16 KB swizzled
  __shared__ ushort Vts[128 * 64];   // 16 KB swizzled
  __shared__ ushort Pls[4][16 * 64]; // 8 KB swizzled, per-wave (wave-ordered DS)

  const int tid = threadIdx.x;
  const int wave = tid >> 6, lane = tid & 63;
  const int quad = lane >> 4, l16 = lane & 15;

  const ushort* Kb  = K  + (size_t)b * T_SEQ * D_DIM;
  const ushort* Vtb = Vt + (size_t)b * D_DIM * T_SEQ;

  const int skn_ = tid >> 4, skp_ = tid & 15;
  const int svd_ = tid >> 3, svp_ = tid & 7;

#define DMA_K(kt_)                                                              \
  _Pragma("unroll")                                                             \
  for (int i_ = 0; i_ < 4; i_++) {                                              \
    int slotbase = i_ * 256 + wave * 64;                                        \
    int n = i_ * 16 + skn_;                                                     \
    int cg = skp_ ^ (n & 7);                                                    \
    gl2lds16(Kb + (size_t)((kt_) * 64 + n) * D_DIM + cg * 8,                    \
             (char*)Kt + (size_t)slotbase * 16);                                \
  }

#define DMA_V(kt_)                                                              \
  _Pragma("unroll")                                                             \
  for (int i_ = 0; i_ < 4; i_++) {                                              \
    int slotbase = i_ * 256 + wave * 64;                                        \
    int d = i_ * 32 + svd_;                                                     \
    int cg = svp_ ^ (d & 7);                                                    \
    gl2lds16(Vtb + (size_t)d * T_SEQ + (kt_) * 64 + cg * 8,                     \
             (char*)Vts + (size_t)slotbase * 16);                               \
  }

  const int qrow = qt * 64 + wave * 16 + l16;
  bf16x8 qf[4];
#pragma unroll
  for (int kk = 0; kk < 4; kk++)
    qf[kk] = *(const bf16x8*)(Q + (size_t)(b * T_SEQ + qrow) * D_DIM + kk * 32 + quad * 8);

  bf16x8 ones;
#pragma unroll
  for (int j = 0; j < 8; j++) ones[j] = (short)0x3F80;  // bf16 1.0

  f32x4 o_acc[8] = {};
  f32x4 lacc = {};
  const float scale2 = 0.08838834764831845f * 1.4426950408889634f;  // 1/sqrt(128)*log2(e)

  const int kt1 = min(qt, kt0 + CHUNK_KT - 1);

  for (int kt = kt0; kt <= kt1; kt++) {
    __syncthreads();                 // all waves done reading previous tile
    DMA_K(kt);
    DMA_V(kt);
    __syncthreads();                 // vmcnt(0) drain: tile staged

    // QK^T from swizzled LDS
    f32x4 s[4] = {};
#pragma unroll
    for (int kk = 0; kk < 4; kk++) {
#pragma unroll
      for (int ni = 0; ni < 4; ni++) {
        int row = ni * 16 + l16;
        int pg = (kk * 4 + quad) ^ (row & 7);
        bf16x8 bf = *(const bf16x8*)(Kt + row * 128 + pg * 8);
        s[ni] = __builtin_amdgcn_mfma_f32_16x16x32_bf16(qf[kk], bf, s[ni], 0, 0, 0);
      }
    }
    // p = exp2(s*scale2 - SHIFT); causal mask only on diagonal tile
    if (kt == qt) {
#pragma unroll
      for (int ni = 0; ni < 4; ni++) {
        int kidx = kt * 64 + ni * 16 + l16;
#pragma unroll
        for (int r = 0; r < 4; r++) {
          int qidx = qt * 64 + wave * 16 + quad * 4 + r;
          float v = (kidx > qidx) ? -1e30f : (s[ni][r] * scale2 - SM_SHIFT);
          s[ni][r] = exp2f(v);
        }
      }
    } else {
#pragma unroll
      for (int ni = 0; ni < 4; ni++)
#pragma unroll
        for (int r = 0; r < 4; r++)
          s[ni][r] = exp2f(s[ni][r] * scale2 - SM_SHIFT);
    }
    // P scatter into swizzled per-wave slice
#pragma unroll
    for (int ni = 0; ni < 4; ni++)
#pragma unroll
      for (int r = 0; r < 4; r++) {
        int row = quad * 4 + r;
        int col = ni * 16 + l16;
        Pls[wave][row * 64 + (((col >> 3) ^ (row & 7)) * 8) + (col & 7)] = f2bf(s[ni][r]);
      }
    // PV from swizzled LDS
#pragma unroll
    for (int kk2 = 0; kk2 < 2; kk2++) {
      bf16x8 pf = *(const bf16x8*)(&Pls[wave][l16 * 64 + (((kk2 * 4 + quad) ^ (l16 & 7)) * 8)]);
#pragma unroll
      for (int ni = 0; ni < 8; ni++) {
        int row = ni * 16 + l16;
        int pg = (kk2 * 4 + quad) ^ (row & 7);
        bf16x8 vf = *(const bf16x8*)(Vts + row * 64 + pg * 8);
        o_acc[ni] = __builtin_amdgcn_mfma_f32_16x16x32_bf16(pf, vf, o_acc[ni], 0, 0, 0);
      }
      lacc = __builtin_amdgcn_mfma_f32_16x16x32_bf16(pf, ones, lacc, 0, 0, 0);  // row sums
    }
  }

  const int slot = (b * 64 + qt) * NCHUNK + cq;
#pragma unroll
  for (int ni = 0; ni < 8; ni++)
#pragma unroll
    for (int r = 0; r < 4; r++) {
      int ql = wave * 16 + quad * 4 + r;
      Po[(size_t)slot * 8192 + ql * D_DIM + ni * 16 + l16] = f2bf(o_acc[ni][r]);
    }
  if (l16 == 0) {
#pragma unroll
    for (int r = 0; r < 4; r++) {
      int ql = wave * 16 + quad * 4 + r;
      Ll[slot * 64 + ql] = lacc[r];
    }
  }
#undef DMA_K
#undef DMA_V
}

// ---------------- kernel 4: split-K reduce (plain sum, fixed shift) ----------------
__global__ __launch_bounds__(256) void attn_reduce(const ushort* __restrict__ Po,
                                                   const float* __restrict__ Ll,
                                                   float* __restrict__ out) {
  const int qt = blockIdx.x, b = blockIdx.y;
  const int nc = qt / CHUNK_KT + 1;
  const int tid = threadIdx.x;
  const int row = tid >> 2;
  const int c0  = (tid & 3) * 32;
  const int base_slot = (b * 64 + qt) * NCHUNK;

  float L = 0.f;
  for (int c = 0; c < nc; c++) L += Ll[(base_slot + c) * 64 + row];
  const float inv = 1.0f / L;

  const size_t orow = (size_t)(b * T_SEQ + qt * 64 + row) * D_DIM;
  for (int cc = 0; cc < 32; cc += 8) {
    float a[8] = {0,0,0,0,0,0,0,0};
    for (int c = 0; c < nc; c++) {
      const ushort* p = Po + (size_t)(base_slot + c) * 8192 + row * D_DIM + c0 + cc;
      ushort u[8];
      *(uint4*)u = *(const uint4*)p;
      for (int j = 0; j < 8; j++) a[j] += bf2f(u[j]);
    }
    float4 o0, o1;
    o0.x = a[0] * inv; o0.y = a[1] * inv; o0.z = a[2] * inv; o0.w = a[3] * inv;
    o1.x = a[4] * inv; o1.y = a[5] * inv; o1.z = a[6] * inv; o1.w = a[7] * inv;
    *(float4*)(out + orow + c0 + cc)     = o0;
    *(float4*)(out + orow + c0 + cc + 4) = o1;
  }
}

extern "C" void kernel_launch(void* const* d_in, const int* in_sizes, int n_in,
                              void* d_out, int out_size, void* d_ws, size_t ws_size,
                              hipStream_t stream) {
  const float* x  = (const float*)d_in[0];
  const float* Wq = (const float*)d_in[1];
  const float* Wk = (const float*)d_in[2];
  const float* Wv = (const float*)d_in[3];
  float* out = (float*)d_out;

  ushort* Q  = (ushort*)d_ws;                       // 16384*128 bf16 each
  ushort* Kb = Q  + (size_t)M_TOT * D_DIM;
  ushort* Vb = Kb + (size_t)M_TOT * D_DIM;          // (slot unused, kept for layout)
  ushort* Vt = Vb + (size_t)M_TOT * D_DIM;
  ushort* Wt = Vt + (size_t)M_TOT * D_DIM;          // 384*2048 bf16
  ushort* Po = Wt + (size_t)384 * E_DIM;            // (NB*64*NCHUNK) slots * 8192 bf16
  float*  Ll = (float*)(Po + (size_t)NB * 64 * NCHUNK * 8192);
  ushort* xbf = (ushort*)(Ll + (size_t)NB * 64 * NCHUNK * 64);  // 16384*2048 bf16 (67MB)

  const size_t needed = (size_t)((char*)(xbf + (size_t)M_TOT * E_DIM) - (char*)d_ws);

  hipLaunchKernelGGL(build_wt, dim3(32, 2, 3), dim3(256), 0, stream, Wq, Wk, Wv, Wt);
  if (ws_size >= needed) {
    hipLaunchKernelGGL(x_cvt,       dim3(2048),   dim3(256), 0, stream, x, xbf);
    hipLaunchKernelGGL(qkv_gemm_bf, dim3(256, 4), dim3(256), 0, stream, xbf, Wt, Q, Kb, Vt);
  } else {
    hipLaunchKernelGGL(qkv_gemm,    dim3(256, 4), dim3(256), 0, stream, x, Wt, Q, Kb, Vt);
  }
  hipLaunchKernelGGL(attn_partial, dim3(64, NCHUNK, 4), dim3(256), 0, stream, Q, Kb, Vt, Po, Ll);
  hipLaunchKernelGGL(attn_reduce,  dim3(64, 4),         dim3(256), 0, stream, Po, Ll, out);
}